// Round 3
// baseline (619.128 us; speedup 1.0000x reference)
//
#include <hip/hip_runtime.h>
#include <math.h>
#include <stdint.h>

// ---------------- problem constants ----------------
#define T_TOK  8192
#define DMODEL 1024
#define DFF    4096
#define NEXP   8
#define MAXTILES 71      // sum ceil(cnt_e/128) <= 64 + (NEXP-1)
#define NRBLK  (T_TOK / 4)   // router blocks (4 tokens each) = 2048

// ---------------- workspace layout (bytes) ----------------
static constexpr size_t OFF_COUNTS  = 0;
static constexpr size_t OFF_EIDX    = 1024;
static constexpr size_t OFF_EW      = OFF_EIDX + (size_t)T_TOK * 4;
static constexpr size_t OFF_PERM    = OFF_EW   + (size_t)T_TOK * 4;
static constexpr size_t OFF_HIST    = OFF_PERM + (size_t)T_TOK * 4;   // u8 [2048][8]
static constexpr size_t OFF_XB      = 131072;                                   // bf16 x  [T][D]
static constexpr size_t OFF_W1B     = OFF_XB  + (size_t)T_TOK * DMODEL * 2;     // bf16 w1^T [E][DFF][D]
static constexpr size_t OFF_W2B     = OFF_W1B + (size_t)NEXP * DFF * DMODEL * 2;// bf16 w2^T [E][D][DFF]
static constexpr size_t OFF_HB      = OFF_W2B + (size_t)NEXP * DMODEL * DFF * 2;// bf16 h  [T][DFF] grouped

typedef __attribute__((ext_vector_type(8))) short short8;
typedef __attribute__((ext_vector_type(4))) float floatx4;

__device__ __forceinline__ unsigned short f2bf(float f) {
    unsigned u = __builtin_bit_cast(unsigned, f);
    u += 0x7fffu + ((u >> 16) & 1u);   // round-to-nearest-even
    return (unsigned short)(u >> 16);
}

__device__ __forceinline__ void async16(const unsigned short* g, unsigned short* l) {
    __builtin_amdgcn_global_load_lds(
        (const __attribute__((address_space(1))) unsigned*)g,
        (__attribute__((address_space(3))) unsigned*)l, 16, 0, 0);
}

// tanh-form GELU via sigmoid: gelu(x) ~= x * sigmoid(2*sqrt(2/pi)*(x+0.044715x^3))
// max abs error vs exact-erf GELU ~3e-4, far below bf16 quantization of h.
__device__ __forceinline__ float gelu_fast(float v) {
    float u2 = v * (1.5957691216f + 0.0713548163f * v * v);
    return v / (1.0f + __expf(-u2));
}

// Per-block tile table: ti -> (expert, m-tile, group offset, count), -1 past end.
__device__ __forceinline__ int tile_lookup(const int* __restrict__ counts,
                                           int ti, int& mt, int& off, int& cnt) {
    int s = 0, acc = 0, e = -1;
#pragma unroll
    for (int ee = 0; ee < NEXP; ee++) {
        int c = counts[ee];
        int m = (c + 127) >> 7;
        if (e < 0 && ti < acc + m) { e = ee; mt = ti - acc; off = s; cnt = c; }
        acc += m; s += c;
    }
    return e;
}

// ---------------- fused prep: BOTH weight transposes + router in one dispatch ----
// Flat grid of 10240 blocks, round-robin over 5 slots:
//   f%5 in {0,1} -> w1 transpose block (4096 total)
//   f%5 in {2,3} -> w2 transpose block (4096 total)
//   f%5 == 4     -> router block      (2048 total, 4 tokens each)
// All blocks are independent (no cross-type ordering needed). Shared 32 KiB
// LDS region is a union: transpose tile OR router gwT. Router emits a per-block
// u8 histogram (plain stores) instead of atomics into counts -> NO zero-init
// of workspace is required anywhere.
__global__ __launch_bounds__(256) void prep_kernel(
    const float* __restrict__ x,  const float* __restrict__ gw,
    const float* __restrict__ w1, const float* __restrict__ w2,
    unsigned short* __restrict__ w1b, unsigned short* __restrict__ w2b,
    unsigned short* __restrict__ xb,
    int* __restrict__ eidx, float* __restrict__ ew,
    unsigned char* __restrict__ hist8)
{
    __shared__ __attribute__((aligned(16))) char smem[32768];
    const int tid = threadIdx.x;
    const int f = blockIdx.x;
    const int q = f / 5, m = f - q * 5;

    if (m == 4) {
        // ---------------- router block (4 tokens: q*4 .. q*4+3) ----------------
        float (*gwT)[DMODEL] = (float (*)[DMODEL])smem;
        int lane = tid & 63, w = tid >> 6;
        {   // cooperative load gw [1024][8] -> gwT[e][d]; 4 d-rows per thread
            int d0 = tid * 4;
            const float* g = gw + (size_t)d0 * NEXP;
            float4 a0 = *(const float4*)(g +  0), b0 = *(const float4*)(g +  4);
            float4 a1 = *(const float4*)(g +  8), b1 = *(const float4*)(g + 12);
            float4 a2 = *(const float4*)(g + 16), b2 = *(const float4*)(g + 20);
            float4 a3 = *(const float4*)(g + 24), b3 = *(const float4*)(g + 28);
            *(float4*)&gwT[0][d0] = float4{a0.x, a1.x, a2.x, a3.x};
            *(float4*)&gwT[1][d0] = float4{a0.y, a1.y, a2.y, a3.y};
            *(float4*)&gwT[2][d0] = float4{a0.z, a1.z, a2.z, a3.z};
            *(float4*)&gwT[3][d0] = float4{a0.w, a1.w, a2.w, a3.w};
            *(float4*)&gwT[4][d0] = float4{b0.x, b1.x, b2.x, b3.x};
            *(float4*)&gwT[5][d0] = float4{b0.y, b1.y, b2.y, b3.y};
            *(float4*)&gwT[6][d0] = float4{b0.z, b1.z, b2.z, b3.z};
            *(float4*)&gwT[7][d0] = float4{b0.w, b1.w, b2.w, b3.w};
        }
        __syncthreads();

        int t = q * 4 + w;
        float acc[NEXP];
#pragma unroll
        for (int e = 0; e < NEXP; e++) acc[e] = 0.f;
        const float* xr = x + (size_t)t * DMODEL;
        unsigned short* xbr = xb + (size_t)t * DMODEL;
#pragma unroll
        for (int i = 0; i < 4; i++) {
            int dbase = i * 256 + lane * 4;
            float4 xv = *(const float4*)(xr + dbase);
            uint2 p;
            p.x = (unsigned)f2bf(xv.x) | ((unsigned)f2bf(xv.y) << 16);
            p.y = (unsigned)f2bf(xv.z) | ((unsigned)f2bf(xv.w) << 16);
            *(uint2*)(xbr + dbase) = p;
#pragma unroll
            for (int e = 0; e < NEXP; e++) {
                float4 g = *(const float4*)&gwT[e][dbase];   // ds_read_b128
                acc[e] += xv.x * g.x + xv.y * g.y + xv.z * g.z + xv.w * g.w;
            }
        }
#pragma unroll
        for (int e = 0; e < NEXP; e++) {
#pragma unroll
            for (int o = 32; o > 0; o >>= 1) acc[e] += __shfl_xor(acc[e], o, 64);
        }
        float mx = acc[0]; int a = 0;
#pragma unroll
        for (int e = 1; e < NEXP; e++) { if (acc[e] > mx) { mx = acc[e]; a = e; } }
        float s = 0.f;
#pragma unroll
        for (int e = 0; e < NEXP; e++) s += expf(acc[e] - mx);

        // histogram: alias lh onto smem AFTER all gwT reads are done
        __syncthreads();
        int* lh = (int*)smem;
        if (tid < NEXP) lh[tid] = 0;
        __syncthreads();
        if (lane == 0) { eidx[t] = a; ew[t] = 1.0f / s; atomicAdd(&lh[a], 1); }
        __syncthreads();
        if (tid < NEXP) hist8[(size_t)q * NEXP + tid] = (unsigned char)lh[tid];
        return;
    }

    // ---------------- transpose block: src [K][N] fp32 -> dst [N][K] bf16 ------
    const bool isw2 = (m >= 2);
    const int id = q * 2 + (m & 1);
    const int e  = id >> 9, r = id & 511;
    int kt, nt, K, N;
    const float* src; unsigned short* dst;
    if (!isw2) { K = DMODEL; N = DFF;    kt = r & 7;  nt = r >> 3; src = w1; dst = w1b; }
    else       { K = DFF;    N = DMODEL; kt = r & 31; nt = r >> 5; src = w2; dst = w2b; }
    src += (size_t)e * K * N;
    dst += (size_t)e * K * N;
    const int k0 = kt * 128, n0 = nt * 64;

    unsigned (*tp)[66] = (unsigned (*)[66])smem;   // [n][packed k-pair]

    {   // phase 1: hoist all 8 global 16B loads, then convert+pack+LDS-write
        const int kp = tid >> 4;   // k-pair 0..15
        const int nq = tid & 15;   // n-quad 0..15
        const float* s0 = src + (size_t)(k0 + 2 * kp) * N + n0 + nq * 4;
        float4 va[4], vb[4];
#pragma unroll
        for (int i = 0; i < 4; i++) {
            const float* sr = s0 + (size_t)(i * 32) * N;
            va[i] = *(const float4*)(sr);
            vb[i] = *(const float4*)(sr + N);
        }
#pragma unroll
        for (int i = 0; i < 4; i++) {
            int kw = i * 16 + kp;
            tp[nq * 4 + 0][kw] = (unsigned)f2bf(va[i].x) | ((unsigned)f2bf(vb[i].x) << 16);
            tp[nq * 4 + 1][kw] = (unsigned)f2bf(va[i].y) | ((unsigned)f2bf(vb[i].y) << 16);
            tp[nq * 4 + 2][kw] = (unsigned)f2bf(va[i].z) | ((unsigned)f2bf(vb[i].z) << 16);
            tp[nq * 4 + 3][kw] = (unsigned)f2bf(va[i].w) | ((unsigned)f2bf(vb[i].w) << 16);
        }
    }
    __syncthreads();
    {   // phase 2: each dst row = 256B; 8 lanes x 16B -> full 128B-line stores
        const int g0 = tid & 7, nl = tid >> 3;   // nl 0..31
#pragma unroll
        for (int p = 0; p < 2; p++) {
            int n = p * 32 + nl;
            unsigned short* drow = dst + (size_t)(n0 + n) * K + k0;
#pragma unroll
            for (int h = 0; h < 2; h++) {
                int g = g0 + 8 * h;                       // 16B granule 0..15
                uint2 u0 = *(const uint2*)&tp[n][g * 4];
                uint2 u1 = *(const uint2*)&tp[n][g * 4 + 2];
                uint4 v; v.x = u0.x; v.y = u0.y; v.z = u1.x; v.w = u1.y;
                *(uint4*)(drow + g * 8) = v;
            }
        }
    }
}

// ---------------- grouping: atomic-free scatter via router histograms ----------
// Block b covers tokens [256b, 256b+256) = router blocks [64b, 64b+64).
// Exact slot: expert_base[e] + (#tokens<256b with expert e) + local rank.
__global__ __launch_bounds__(256) void scatter_kernel(
    const int* __restrict__ eidx, const unsigned char* __restrict__ hist8,
    int* __restrict__ counts, int* __restrict__ perm)
{
    __shared__ int sTot[NEXP], sPre[NEXP], lh[NEXP], lbase[NEXP];
    const int b = blockIdx.x, tid = threadIdx.x;
    const int e = tid >> 5, l = tid & 31;      // 8 experts x 32 lanes
    const int rb0 = b * 64;
    int tot = 0, pre = 0;
    for (int r = l; r < NRBLK; r += 32) {
        int v = (int)hist8[(size_t)r * NEXP + e];
        tot += v;
        if (r < rb0) pre += v;
    }
#pragma unroll
    for (int o = 16; o > 0; o >>= 1) {
        tot += __shfl_xor(tot, o, 32);
        pre += __shfl_xor(pre, o, 32);
    }
    if (l == 0) { sTot[e] = tot; sPre[e] = pre; }
    if (tid < NEXP) lh[tid] = 0;
    __syncthreads();
    int t = b * 256 + tid;
    int me = eidx[t];
    int lpos = atomicAdd(&lh[me], 1);          // LDS atomic only
    __syncthreads();
    if (tid < NEXP) {
        int eb = 0;
        for (int i = 0; i < tid; i++) eb += sTot[i];
        lbase[tid] = eb + sPre[tid];
        if (b == 0) counts[tid] = sTot[tid];
    }
    __syncthreads();
    perm[lbase[me] + lpos] = t;
}

// ---------------- GEMM1: h = gelu(x[perm] @ w1 + b1), bf16 MFMA ----------------
// Ping-pong double-buffered LDS (T3 minimum 2-phase): next k-tile's
// global_load_lds issues BEFORE computing the current buffer, so the
// vmcnt(0) drain inside __syncthreads lands after a full compute phase.
// One barrier per k-step; no raw-barrier race surface.
// __launch_bounds__(256,2): 2 blocks/CU (LDS 64KiB/block -> 128KiB/CU).
__global__ __launch_bounds__(256, 2) void gemm1_kernel(
    const unsigned short* __restrict__ xb,
    const unsigned short* __restrict__ w1b,   // [E][DFF][DMODEL]
    const float* __restrict__ b1,             // [E][DFF]
    const int* __restrict__ counts,
    const int* __restrict__ perm,
    unsigned short* __restrict__ hb)          // [T][DFF] grouped rows
{
    int mt, off, cnt;
    const int e = tile_lookup(counts, blockIdx.y, mt, off, cnt);
    if (e < 0) return;
    const int nt = blockIdx.x;
    const int tid = threadIdx.x, lane = tid & 63, wave = tid >> 6;
    const int wm = (wave >> 1) * 64, wn = (wave & 1) * 64;
    const int lm = lane & 15, quad = lane >> 4;

    __shared__ __attribute__((aligned(16))) unsigned short As[2][128 * 64];
    __shared__ __attribute__((aligned(16))) unsigned short Bs[2][128 * 64];

    const unsigned short* a_src[4];
    const unsigned short* b_src[4];
    const int cntLoc = cnt - mt * 128;
#pragma unroll
    for (int i = 0; i < 4; i++) {
        int c = i * 256 + tid;
        int row = c >> 3;
        int g = (c & 7) ^ (row & 7);          // XOR-swizzled 16B granule
        int r = (row < cntLoc) ? row : 0;
        int tok = perm[off + mt * 128 + r];
        a_src[i] = xb + (size_t)tok * DMODEL + g * 8;
        b_src[i] = w1b + ((size_t)e * DFF + nt * 128 + row) * DMODEL + g * 8;
    }

    floatx4 acc[4][4];
#pragma unroll
    for (int i = 0; i < 4; i++)
#pragma unroll
        for (int j = 0; j < 4; j++) acc[i][j] = floatx4{0.f, 0.f, 0.f, 0.f};

#define G1_STAGE(buf, koff)                                           \
    _Pragma("unroll")                                                 \
    for (int i = 0; i < 4; i++) {                                     \
        async16(a_src[i] + (koff), &As[buf][(i * 256 + tid) * 8]);    \
        async16(b_src[i] + (koff), &Bs[buf][(i * 256 + tid) * 8]);    \
    }

#define G1_COMPUTE(buf)                                               \
    _Pragma("unroll")                                                 \
    for (int kk = 0; kk < 2; kk++) {                                  \
        short8 af[4], bfr[4];                                         \
        _Pragma("unroll")                                             \
        for (int im = 0; im < 4; im++) {                              \
            int m2 = wm + im * 16 + lm;                               \
            int slot = (kk * 4 + quad) ^ (m2 & 7);                    \
            af[im] = *(const short8*)(&As[buf][m2 * 64 + slot * 8]);  \
        }                                                             \
        _Pragma("unroll")                                             \
        for (int in = 0; in < 4; in++) {                              \
            int n = wn + in * 16 + lm;                                \
            int slot = (kk * 4 + quad) ^ (n & 7);                     \
            bfr[in] = *(const short8*)(&Bs[buf][n * 64 + slot * 8]);  \
        }                                                             \
        _Pragma("unroll")                                             \
        for (int im = 0; im < 4; im++)                                \
            _Pragma("unroll")                                         \
            for (int in = 0; in < 4; in++)                            \
                acc[im][in] = __builtin_amdgcn_mfma_f32_16x16x32_bf16(\
                    af[im], bfr[in], acc[im][in], 0, 0, 0);           \
    }

    G1_STAGE(0, 0)
    __syncthreads();
#pragma unroll 1
    for (int k0 = 0; k0 < DMODEL; k0 += 128) {
        G1_STAGE(1, k0 + 64)          // in flight under compute of buf0
        G1_COMPUTE(0)
        __syncthreads();              // drains buf1 loads + read-fence buf0
        if (k0 + 128 < DMODEL) {
            G1_STAGE(0, k0 + 128)     // in flight under compute of buf1
        }
        G1_COMPUTE(1)
        __syncthreads();
    }
#undef G1_STAGE
#undef G1_COMPUTE

    float b1v[4];
#pragma unroll
    for (int in = 0; in < 4; in++) b1v[in] = b1[e * DFF + nt * 128 + wn + in * 16 + lm];
#pragma unroll
    for (int im = 0; im < 4; im++) {
#pragma unroll
        for (int r = 0; r < 4; r++) {
            int row = mt * 128 + wm + im * 16 + quad * 4 + r;
            if (row < cnt) {
                size_t base = (size_t)(off + row) * DFF + nt * 128 + wn + lm;
#pragma unroll
                for (int in = 0; in < 4; in++) {
                    float v = acc[im][in][r] + b1v[in];
                    hb[base + in * 16] = f2bf(gelu_fast(v));
                }
            }
        }
    }
}

// ---------------- GEMM2: out[tok] = ew[tok]*(h @ w2 + b2) ----------------
// Same ping-pong double-buffer; 512 threads / 8 waves per block.
__global__ __launch_bounds__(512, 4) void gemm2_kernel(
    const unsigned short* __restrict__ hb,    // [T][DFF] grouped
    const unsigned short* __restrict__ w2b,   // [E][DMODEL][DFF]
    const float* __restrict__ b2,             // [E][DMODEL]
    const int* __restrict__ counts,
    const int* __restrict__ perm,
    const float* __restrict__ ew,
    float* __restrict__ out)                  // [T][DMODEL]
{
    int mt, off, cnt;
    const int e = tile_lookup(counts, blockIdx.y, mt, off, cnt);
    if (e < 0) return;
    const int nt = blockIdx.x;
    const int tid = threadIdx.x, lane = tid & 63, wave = tid >> 6;
    const int wm = (wave >> 2) * 64, wn = (wave & 3) * 32;   // 8 waves: 2(M) x 4(N) of 64x32
    const int lm = lane & 15, quad = lane >> 4;

    __shared__ __attribute__((aligned(16))) unsigned short As[2][128 * 64];
    __shared__ __attribute__((aligned(16))) unsigned short Bs[2][128 * 64];

    const unsigned short* a_src[2];
    const unsigned short* b_src[2];
#pragma unroll
    for (int i = 0; i < 2; i++) {
        int c = i * 512 + tid;
        int row = c >> 3;
        int g = (c & 7) ^ (row & 7);
        int gr = off + mt * 128 + row;
        if (gr > T_TOK - 1) gr = T_TOK - 1;
        a_src[i] = hb + (size_t)gr * DFF + g * 8;
        b_src[i] = w2b + ((size_t)e * DMODEL + nt * 128 + row) * DFF + g * 8;
    }

    floatx4 acc[4][2];
#pragma unroll
    for (int i = 0; i < 4; i++)
#pragma unroll
        for (int j = 0; j < 2; j++) acc[i][j] = floatx4{0.f, 0.f, 0.f, 0.f};

#define G2_STAGE(buf, koff)                                           \
    _Pragma("unroll")                                                 \
    for (int i = 0; i < 2; i++) {                                     \
        async16(a_src[i] + (koff), &As[buf][(i * 512 + tid) * 8]);    \
        async16(b_src[i] + (koff), &Bs[buf][(i * 512 + tid) * 8]);    \
    }

#define G2_COMPUTE(buf)                                               \
    _Pragma("unroll")                                                 \
    for (int kk = 0; kk < 2; kk++) {                                  \
        short8 af[4], bfr[2];                                         \
        _Pragma("unroll")                                             \
        for (int im = 0; im < 4; im++) {                              \
            int m2 = wm + im * 16 + lm;                               \
            int slot = (kk * 4 + quad) ^ (m2 & 7);                    \
            af[im] = *(const short8*)(&As[buf][m2 * 64 + slot * 8]);  \
        }                                                             \
        _Pragma("unroll")                                             \
        for (int in = 0; in < 2; in++) {                              \
            int n = wn + in * 16 + lm;                                \
            int slot = (kk * 4 + quad) ^ (n & 7);                     \
            bfr[in] = *(const short8*)(&Bs[buf][n * 64 + slot * 8]);  \
        }                                                             \
        _Pragma("unroll")                                             \
        for (int im = 0; im < 4; im++)                                \
            _Pragma("unroll")                                         \
            for (int in = 0; in < 2; in++)                            \
                acc[im][in] = __builtin_amdgcn_mfma_f32_16x16x32_bf16(\
                    af[im], bfr[in], acc[im][in], 0, 0, 0);           \
    }

    G2_STAGE(0, 0)
    __syncthreads();
#pragma unroll 1
    for (int k0 = 0; k0 < DFF; k0 += 128) {
        G2_STAGE(1, k0 + 64)
        G2_COMPUTE(0)
        __syncthreads();
        if (k0 + 128 < DFF) {
            G2_STAGE(0, k0 + 128)
        }
        G2_COMPUTE(1)
        __syncthreads();
    }
#undef G2_STAGE
#undef G2_COMPUTE

    float b2v[2];
#pragma unroll
    for (int in = 0; in < 2; in++)
        b2v[in] = b2[e * DMODEL + nt * 128 + wn + in * 16 + lm];
#pragma unroll
    for (int im = 0; im < 4; im++) {
#pragma unroll
        for (int r = 0; r < 4; r++) {
            int row = mt * 128 + wm + im * 16 + quad * 4 + r;
            if (row < cnt) {
                int tok = perm[off + row];
                float wv = ew[tok];
                size_t base = (size_t)tok * DMODEL + nt * 128 + wn + lm;
#pragma unroll
                for (int in = 0; in < 2; in++)
                    out[base + in * 16] = (acc[im][in][r] + b2v[in]) * wv;
            }
        }
    }
}

// ---------------- launch ----------------
extern "C" void kernel_launch(void* const* d_in, const int* in_sizes, int n_in,
                              void* d_out, int out_size, void* d_ws, size_t ws_size,
                              hipStream_t stream) {
    const float* x      = (const float*)d_in[0];
    const float* gate_w = (const float*)d_in[1];
    const float* w1     = (const float*)d_in[2];
    const float* b1     = (const float*)d_in[3];
    const float* w2     = (const float*)d_in[4];
    const float* b2     = (const float*)d_in[5];
    float* out = (float*)d_out;
    char* ws = (char*)d_ws;

    int* counts  = (int*)(ws + OFF_COUNTS);
    int* eidx    = (int*)(ws + OFF_EIDX);
    float* ew    = (float*)(ws + OFF_EW);
    int* perm    = (int*)(ws + OFF_PERM);
    unsigned char* hist8 = (unsigned char*)(ws + OFF_HIST);
    unsigned short* xb  = (unsigned short*)(ws + OFF_XB);
    unsigned short* w1b = (unsigned short*)(ws + OFF_W1B);
    unsigned short* w2b = (unsigned short*)(ws + OFF_W2B);
    unsigned short* hb  = (unsigned short*)(ws + OFF_HB);

    {   // transposes (w1: 4096 blocks, w2: 4096) + router (2048), round-robin.
        prep_kernel<<<dim3(10240), 256, 0, stream>>>(x, gate_w, w1, w2,
                                                     w1b, w2b, xb, eidx, ew, hist8);
    }
    scatter_kernel<<<T_TOK / 256, 256, 0, stream>>>(eidx, hist8, counts, perm);
    {
        dim3 g(DFF / 128, MAXTILES);
        gemm1_kernel<<<g, 256, 0, stream>>>(xb, w1b, b1, counts, perm, hb);
    }
    {
        dim3 g(DMODEL / 128, MAXTILES);
        gemm2_kernel<<<g, 512, 0, stream>>>(hb, w2b, b2, counts, perm, ew, out);
    }
}

// Round 4
// 529.934 us; speedup vs baseline: 1.1683x; 1.1683x over previous
//
#include <hip/hip_runtime.h>
#include <math.h>
#include <stdint.h>

// ---------------- problem constants ----------------
#define T_TOK  8192
#define DMODEL 1024
#define DFF    4096
#define NEXP   8
#define MAXTILES 71      // sum ceil(cnt_e/128) <= 64 + (NEXP-1)
#define NRBLK  (T_TOK / 4)   // router blocks (4 tokens each) = 2048

// ---------------- workspace layout (bytes) ----------------
static constexpr size_t OFF_COUNTS  = 0;
static constexpr size_t OFF_EIDX    = 1024;
static constexpr size_t OFF_EW      = OFF_EIDX + (size_t)T_TOK * 4;
static constexpr size_t OFF_PERM    = OFF_EW   + (size_t)T_TOK * 4;
static constexpr size_t OFF_HIST    = OFF_PERM + (size_t)T_TOK * 4;   // u8 [2048][8]
static constexpr size_t OFF_XB      = 131072;                                   // bf16 x  [T][D]
static constexpr size_t OFF_W1B     = OFF_XB  + (size_t)T_TOK * DMODEL * 2;     // bf16 w1^T [E][DFF][D]
static constexpr size_t OFF_W2B     = OFF_W1B + (size_t)NEXP * DFF * DMODEL * 2;// bf16 w2^T [E][D][DFF]
static constexpr size_t OFF_HB      = OFF_W2B + (size_t)NEXP * DMODEL * DFF * 2;// bf16 h  [T][DFF] grouped

typedef __attribute__((ext_vector_type(8))) short short8;
typedef __attribute__((ext_vector_type(4))) float floatx4;

__device__ __forceinline__ unsigned short f2bf(float f) {
    unsigned u = __builtin_bit_cast(unsigned, f);
    u += 0x7fffu + ((u >> 16) & 1u);   // round-to-nearest-even
    return (unsigned short)(u >> 16);
}

__device__ __forceinline__ void async16(const unsigned short* g, unsigned short* l) {
    __builtin_amdgcn_global_load_lds(
        (const __attribute__((address_space(1))) unsigned*)g,
        (__attribute__((address_space(3))) unsigned*)l, 16, 0, 0);
}

// tanh-form GELU via sigmoid: gelu(x) ~= x * sigmoid(2*sqrt(2/pi)*(x+0.044715x^3))
// max abs error vs exact-erf GELU ~3e-4, far below bf16 quantization of h.
__device__ __forceinline__ float gelu_fast(float v) {
    float u2 = v * (1.5957691216f + 0.0713548163f * v * v);
    return v / (1.0f + __expf(-u2));
}

// Per-block tile table: ti -> (expert, m-tile, group offset, count), -1 past end.
__device__ __forceinline__ int tile_lookup(const int* __restrict__ counts,
                                           int ti, int& mt, int& off, int& cnt) {
    int s = 0, acc = 0, e = -1;
#pragma unroll
    for (int ee = 0; ee < NEXP; ee++) {
        int c = counts[ee];
        int m = (c + 127) >> 7;
        if (e < 0 && ti < acc + m) { e = ee; mt = ti - acc; off = s; cnt = c; }
        acc += m; s += c;
    }
    return e;
}

// ---------------- fused prep: BOTH weight transposes + router in one dispatch ----
// Flat grid of 10240 blocks, round-robin over 5 slots:
//   f%5 in {0,1} -> w1 transpose block (4096 total)
//   f%5 in {2,3} -> w2 transpose block (4096 total)
//   f%5 == 4     -> router block      (2048 total, 4 tokens each)
// All blocks are independent (no cross-type ordering needed). Shared 32 KiB
// LDS region is a union: transpose tile OR router gwT. Router emits a per-block
// u8 histogram (plain stores) instead of atomics into counts -> NO zero-init
// of workspace is required anywhere.
__global__ __launch_bounds__(256) void prep_kernel(
    const float* __restrict__ x,  const float* __restrict__ gw,
    const float* __restrict__ w1, const float* __restrict__ w2,
    unsigned short* __restrict__ w1b, unsigned short* __restrict__ w2b,
    unsigned short* __restrict__ xb,
    int* __restrict__ eidx, float* __restrict__ ew,
    unsigned char* __restrict__ hist8)
{
    __shared__ __attribute__((aligned(16))) char smem[32768];
    const int tid = threadIdx.x;
    const int f = blockIdx.x;
    const int q = f / 5, m = f - q * 5;

    if (m == 4) {
        // ---------------- router block (4 tokens: q*4 .. q*4+3) ----------------
        float (*gwT)[DMODEL] = (float (*)[DMODEL])smem;
        int lane = tid & 63, w = tid >> 6;
        {   // cooperative load gw [1024][8] -> gwT[e][d]; 4 d-rows per thread
            int d0 = tid * 4;
            const float* g = gw + (size_t)d0 * NEXP;
            float4 a0 = *(const float4*)(g +  0), b0 = *(const float4*)(g +  4);
            float4 a1 = *(const float4*)(g +  8), b1 = *(const float4*)(g + 12);
            float4 a2 = *(const float4*)(g + 16), b2 = *(const float4*)(g + 20);
            float4 a3 = *(const float4*)(g + 24), b3 = *(const float4*)(g + 28);
            *(float4*)&gwT[0][d0] = float4{a0.x, a1.x, a2.x, a3.x};
            *(float4*)&gwT[1][d0] = float4{a0.y, a1.y, a2.y, a3.y};
            *(float4*)&gwT[2][d0] = float4{a0.z, a1.z, a2.z, a3.z};
            *(float4*)&gwT[3][d0] = float4{a0.w, a1.w, a2.w, a3.w};
            *(float4*)&gwT[4][d0] = float4{b0.x, b1.x, b2.x, b3.x};
            *(float4*)&gwT[5][d0] = float4{b0.y, b1.y, b2.y, b3.y};
            *(float4*)&gwT[6][d0] = float4{b0.z, b1.z, b2.z, b3.z};
            *(float4*)&gwT[7][d0] = float4{b0.w, b1.w, b2.w, b3.w};
        }
        __syncthreads();

        int t = q * 4 + w;
        float acc[NEXP];
#pragma unroll
        for (int e = 0; e < NEXP; e++) acc[e] = 0.f;
        const float* xr = x + (size_t)t * DMODEL;
        unsigned short* xbr = xb + (size_t)t * DMODEL;
#pragma unroll
        for (int i = 0; i < 4; i++) {
            int dbase = i * 256 + lane * 4;
            float4 xv = *(const float4*)(xr + dbase);
            uint2 p;
            p.x = (unsigned)f2bf(xv.x) | ((unsigned)f2bf(xv.y) << 16);
            p.y = (unsigned)f2bf(xv.z) | ((unsigned)f2bf(xv.w) << 16);
            *(uint2*)(xbr + dbase) = p;
#pragma unroll
            for (int e = 0; e < NEXP; e++) {
                float4 g = *(const float4*)&gwT[e][dbase];   // ds_read_b128
                acc[e] += xv.x * g.x + xv.y * g.y + xv.z * g.z + xv.w * g.w;
            }
        }
#pragma unroll
        for (int e = 0; e < NEXP; e++) {
#pragma unroll
            for (int o = 32; o > 0; o >>= 1) acc[e] += __shfl_xor(acc[e], o, 64);
        }
        float mx = acc[0]; int a = 0;
#pragma unroll
        for (int e = 1; e < NEXP; e++) { if (acc[e] > mx) { mx = acc[e]; a = e; } }
        float s = 0.f;
#pragma unroll
        for (int e = 0; e < NEXP; e++) s += expf(acc[e] - mx);

        // histogram: alias lh onto smem AFTER all gwT reads are done
        __syncthreads();
        int* lh = (int*)smem;
        if (tid < NEXP) lh[tid] = 0;
        __syncthreads();
        if (lane == 0) { eidx[t] = a; ew[t] = 1.0f / s; atomicAdd(&lh[a], 1); }
        __syncthreads();
        if (tid < NEXP) hist8[(size_t)q * NEXP + tid] = (unsigned char)lh[tid];
        return;
    }

    // ---------------- transpose block: src [K][N] fp32 -> dst [N][K] bf16 ------
    const bool isw2 = (m >= 2);
    const int id = q * 2 + (m & 1);
    const int e  = id >> 9, r = id & 511;
    int kt, nt, K, N;
    const float* src; unsigned short* dst;
    if (!isw2) { K = DMODEL; N = DFF;    kt = r & 7;  nt = r >> 3; src = w1; dst = w1b; }
    else       { K = DFF;    N = DMODEL; kt = r & 31; nt = r >> 5; src = w2; dst = w2b; }
    src += (size_t)e * K * N;
    dst += (size_t)e * K * N;
    const int k0 = kt * 128, n0 = nt * 64;

    unsigned (*tp)[66] = (unsigned (*)[66])smem;   // [n][packed k-pair]

    {   // phase 1: hoist all 8 global 16B loads, then convert+pack+LDS-write
        const int kp = tid >> 4;   // k-pair 0..15
        const int nq = tid & 15;   // n-quad 0..15
        const float* s0 = src + (size_t)(k0 + 2 * kp) * N + n0 + nq * 4;
        float4 va[4], vb[4];
#pragma unroll
        for (int i = 0; i < 4; i++) {
            const float* sr = s0 + (size_t)(i * 32) * N;
            va[i] = *(const float4*)(sr);
            vb[i] = *(const float4*)(sr + N);
        }
#pragma unroll
        for (int i = 0; i < 4; i++) {
            int kw = i * 16 + kp;
            tp[nq * 4 + 0][kw] = (unsigned)f2bf(va[i].x) | ((unsigned)f2bf(vb[i].x) << 16);
            tp[nq * 4 + 1][kw] = (unsigned)f2bf(va[i].y) | ((unsigned)f2bf(vb[i].y) << 16);
            tp[nq * 4 + 2][kw] = (unsigned)f2bf(va[i].z) | ((unsigned)f2bf(vb[i].z) << 16);
            tp[nq * 4 + 3][kw] = (unsigned)f2bf(va[i].w) | ((unsigned)f2bf(vb[i].w) << 16);
        }
    }
    __syncthreads();
    {   // phase 2: each dst row = 256B; 8 lanes x 16B -> full 128B-line stores
        const int g0 = tid & 7, nl = tid >> 3;   // nl 0..31
#pragma unroll
        for (int p = 0; p < 2; p++) {
            int n = p * 32 + nl;
            unsigned short* drow = dst + (size_t)(n0 + n) * K + k0;
#pragma unroll
            for (int h = 0; h < 2; h++) {
                int g = g0 + 8 * h;                       // 16B granule 0..15
                uint2 u0 = *(const uint2*)&tp[n][g * 4];
                uint2 u1 = *(const uint2*)&tp[n][g * 4 + 2];
                uint4 v; v.x = u0.x; v.y = u0.y; v.z = u1.x; v.w = u1.y;
                *(uint4*)(drow + g * 8) = v;
            }
        }
    }
}

// ---------------- grouping: atomic-free scatter via router histograms ----------
// Block b covers tokens [256b, 256b+256) = router blocks [64b, 64b+64).
// Exact slot: expert_base[e] + (#tokens<256b with expert e) + local rank.
__global__ __launch_bounds__(256) void scatter_kernel(
    const int* __restrict__ eidx, const unsigned char* __restrict__ hist8,
    int* __restrict__ counts, int* __restrict__ perm)
{
    __shared__ int sTot[NEXP], sPre[NEXP], lh[NEXP], lbase[NEXP];
    const int b = blockIdx.x, tid = threadIdx.x;
    const int e = tid >> 5, l = tid & 31;      // 8 experts x 32 lanes
    const int rb0 = b * 64;
    int tot = 0, pre = 0;
    for (int r = l; r < NRBLK; r += 32) {
        int v = (int)hist8[(size_t)r * NEXP + e];
        tot += v;
        if (r < rb0) pre += v;
    }
#pragma unroll
    for (int o = 16; o > 0; o >>= 1) {
        tot += __shfl_xor(tot, o, 32);
        pre += __shfl_xor(pre, o, 32);
    }
    if (l == 0) { sTot[e] = tot; sPre[e] = pre; }
    if (tid < NEXP) lh[tid] = 0;
    __syncthreads();
    int t = b * 256 + tid;
    int me = eidx[t];
    int lpos = atomicAdd(&lh[me], 1);          // LDS atomic only
    __syncthreads();
    if (tid < NEXP) {
        int eb = 0;
        for (int i = 0; i < tid; i++) eb += sTot[i];
        lbase[tid] = eb + sPre[tid];
        if (b == 0) counts[tid] = sTot[tid];
    }
    __syncthreads();
    perm[lbase[me] + lpos] = t;
}

// ---------------- GEMM1: h = gelu(x[perm] @ w1 + b1), bf16 MFMA ----------------
// Single-buffer R2 structure (dbuf regressed: 64KiB LDS halved occupancy).
// XCD-chunked swizzle (T1): flat grid 2272 = 32(nt) x 71(ti); remap so each
// XCD owns a contiguous run of ti-rows with nt innermost -> the 32 blocks
// sharing one A-panel (and one expert's w1 slice) land on ONE per-XCD L2.
// Bijective since 2272 % 8 == 0.
// __launch_bounds__(256,2): 2 resident blocks/CU is the cache-friendly point —
// (256,4) raised occupancy to 37% but blew FETCH 107->184MB / WRITE 65->111MB.
__global__ __launch_bounds__(256, 2) void gemm1_kernel(
    const unsigned short* __restrict__ xb,
    const unsigned short* __restrict__ w1b,   // [E][DFF][DMODEL]
    const float* __restrict__ b1,             // [E][DFF]
    const int* __restrict__ counts,
    const int* __restrict__ perm,
    unsigned short* __restrict__ hb)          // [T][DFF] grouped rows
{
    const int l = blockIdx.x;                     // 0..2271
    const int wl = (l & 7) * (32 * MAXTILES / 8) + (l >> 3);
    const int ti = wl >> 5, nt = wl & 31;
    int mt, off, cnt;
    const int e = tile_lookup(counts, ti, mt, off, cnt);
    if (e < 0) return;
    const int tid = threadIdx.x, lane = tid & 63, wave = tid >> 6;
    const int wm = (wave >> 1) * 64, wn = (wave & 1) * 64;
    const int lm = lane & 15, quad = lane >> 4;

    __shared__ __attribute__((aligned(16))) unsigned short As[128 * 64];
    __shared__ __attribute__((aligned(16))) unsigned short Bs[128 * 64];

    const unsigned short* a_src[4];
    const unsigned short* b_src[4];
    const int cntLoc = cnt - mt * 128;
#pragma unroll
    for (int i = 0; i < 4; i++) {
        int c = i * 256 + tid;
        int row = c >> 3;
        int g = (c & 7) ^ (row & 7);          // XOR-swizzled 16B granule
        int r = (row < cntLoc) ? row : 0;
        int tok = perm[off + mt * 128 + r];
        a_src[i] = xb + (size_t)tok * DMODEL + g * 8;
        b_src[i] = w1b + ((size_t)e * DFF + nt * 128 + row) * DMODEL + g * 8;
    }

    floatx4 acc[4][4];
#pragma unroll
    for (int i = 0; i < 4; i++)
#pragma unroll
        for (int j = 0; j < 4; j++) acc[i][j] = floatx4{0.f, 0.f, 0.f, 0.f};

    for (int k0 = 0; k0 < DMODEL; k0 += 64) {
#pragma unroll
        for (int i = 0; i < 4; i++) {
            async16(a_src[i] + k0, &As[(i * 256 + tid) * 8]);
            async16(b_src[i] + k0, &Bs[(i * 256 + tid) * 8]);
        }
        __syncthreads();
#pragma unroll
        for (int kk = 0; kk < 2; kk++) {
            short8 af[4], bfr[4];
#pragma unroll
            for (int im = 0; im < 4; im++) {
                int m2 = wm + im * 16 + lm;
                int slot = (kk * 4 + quad) ^ (m2 & 7);
                af[im] = *(const short8*)(&As[m2 * 64 + slot * 8]);
            }
#pragma unroll
            for (int in = 0; in < 4; in++) {
                int n = wn + in * 16 + lm;
                int slot = (kk * 4 + quad) ^ (n & 7);
                bfr[in] = *(const short8*)(&Bs[n * 64 + slot * 8]);
            }
#pragma unroll
            for (int im = 0; im < 4; im++)
#pragma unroll
                for (int in = 0; in < 4; in++)
                    acc[im][in] = __builtin_amdgcn_mfma_f32_16x16x32_bf16(
                        af[im], bfr[in], acc[im][in], 0, 0, 0);
        }
        __syncthreads();
    }

    float b1v[4];
#pragma unroll
    for (int in = 0; in < 4; in++) b1v[in] = b1[e * DFF + nt * 128 + wn + in * 16 + lm];
#pragma unroll
    for (int im = 0; im < 4; im++) {
#pragma unroll
        for (int r = 0; r < 4; r++) {
            int row = mt * 128 + wm + im * 16 + quad * 4 + r;
            if (row < cnt) {
                size_t base = (size_t)(off + row) * DFF + nt * 128 + wn + lm;
#pragma unroll
                for (int in = 0; in < 4; in++) {
                    float v = acc[im][in][r] + b1v[in];
                    hb[base + in * 16] = f2bf(gelu_fast(v));
                }
            }
        }
    }
}

// ---------------- GEMM2: out[tok] = ew[tok]*(h @ w2 + b2) ----------------
// Single-buffer R2 structure + XCD-chunked swizzle: flat grid 568 = 8 x 71;
// the 8 nt-blocks sharing one hb A-panel run on the same XCD (568 % 8 == 0).
// 512 threads / 8 waves per block: wave count is the latency-hiding lever.
__global__ __launch_bounds__(512, 4) void gemm2_kernel(
    const unsigned short* __restrict__ hb,    // [T][DFF] grouped
    const unsigned short* __restrict__ w2b,   // [E][DMODEL][DFF]
    const float* __restrict__ b2,             // [E][DMODEL]
    const int* __restrict__ counts,
    const int* __restrict__ perm,
    const float* __restrict__ ew,
    float* __restrict__ out)                  // [T][DMODEL]
{
    const int l = blockIdx.x;                     // 0..567
    const int wl = (l & 7) * MAXTILES + (l >> 3);
    const int ti = wl >> 3, nt = wl & 7;
    int mt, off, cnt;
    const int e = tile_lookup(counts, ti, mt, off, cnt);
    if (e < 0) return;
    const int tid = threadIdx.x, lane = tid & 63, wave = tid >> 6;
    const int wm = (wave >> 2) * 64, wn = (wave & 3) * 32;   // 8 waves: 2(M) x 4(N) of 64x32
    const int lm = lane & 15, quad = lane >> 4;

    __shared__ __attribute__((aligned(16))) unsigned short As[128 * 64];
    __shared__ __attribute__((aligned(16))) unsigned short Bs[128 * 64];

    const unsigned short* a_src[2];
    const unsigned short* b_src[2];
#pragma unroll
    for (int i = 0; i < 2; i++) {
        int c = i * 512 + tid;
        int row = c >> 3;
        int g = (c & 7) ^ (row & 7);
        int gr = off + mt * 128 + row;
        if (gr > T_TOK - 1) gr = T_TOK - 1;
        a_src[i] = hb + (size_t)gr * DFF + g * 8;
        b_src[i] = w2b + ((size_t)e * DMODEL + nt * 128 + row) * DFF + g * 8;
    }

    floatx4 acc[4][2];
#pragma unroll
    for (int i = 0; i < 4; i++)
#pragma unroll
        for (int j = 0; j < 2; j++) acc[i][j] = floatx4{0.f, 0.f, 0.f, 0.f};

    for (int k0 = 0; k0 < DFF; k0 += 64) {
#pragma unroll
        for (int i = 0; i < 2; i++) {
            async16(a_src[i] + k0, &As[(i * 512 + tid) * 8]);
            async16(b_src[i] + k0, &Bs[(i * 512 + tid) * 8]);
        }
        __syncthreads();
#pragma unroll
        for (int kk = 0; kk < 2; kk++) {
            short8 af[4], bfr[2];
#pragma unroll
            for (int im = 0; im < 4; im++) {
                int m2 = wm + im * 16 + lm;
                int slot = (kk * 4 + quad) ^ (m2 & 7);
                af[im] = *(const short8*)(&As[m2 * 64 + slot * 8]);
            }
#pragma unroll
            for (int in = 0; in < 2; in++) {
                int n = wn + in * 16 + lm;
                int slot = (kk * 4 + quad) ^ (n & 7);
                bfr[in] = *(const short8*)(&Bs[n * 64 + slot * 8]);
            }
#pragma unroll
            for (int im = 0; im < 4; im++)
#pragma unroll
                for (int in = 0; in < 2; in++)
                    acc[im][in] = __builtin_amdgcn_mfma_f32_16x16x32_bf16(
                        af[im], bfr[in], acc[im][in], 0, 0, 0);
        }
        __syncthreads();
    }

    float b2v[2];
#pragma unroll
    for (int in = 0; in < 2; in++)
        b2v[in] = b2[e * DMODEL + nt * 128 + wn + in * 16 + lm];
#pragma unroll
    for (int im = 0; im < 4; im++) {
#pragma unroll
        for (int r = 0; r < 4; r++) {
            int row = mt * 128 + wm + im * 16 + quad * 4 + r;
            if (row < cnt) {
                int tok = perm[off + row];
                float wv = ew[tok];
                size_t base = (size_t)tok * DMODEL + nt * 128 + wn + lm;
#pragma unroll
                for (int in = 0; in < 2; in++)
                    out[base + in * 16] = (acc[im][in][r] + b2v[in]) * wv;
            }
        }
    }
}

// ---------------- launch ----------------
extern "C" void kernel_launch(void* const* d_in, const int* in_sizes, int n_in,
                              void* d_out, int out_size, void* d_ws, size_t ws_size,
                              hipStream_t stream) {
    const float* x      = (const float*)d_in[0];
    const float* gate_w = (const float*)d_in[1];
    const float* w1     = (const float*)d_in[2];
    const float* b1     = (const float*)d_in[3];
    const float* w2     = (const float*)d_in[4];
    const float* b2     = (const float*)d_in[5];
    float* out = (float*)d_out;
    char* ws = (char*)d_ws;

    int* counts  = (int*)(ws + OFF_COUNTS);
    int* eidx    = (int*)(ws + OFF_EIDX);
    float* ew    = (float*)(ws + OFF_EW);
    int* perm    = (int*)(ws + OFF_PERM);
    unsigned char* hist8 = (unsigned char*)(ws + OFF_HIST);
    unsigned short* xb  = (unsigned short*)(ws + OFF_XB);
    unsigned short* w1b = (unsigned short*)(ws + OFF_W1B);
    unsigned short* w2b = (unsigned short*)(ws + OFF_W2B);
    unsigned short* hb  = (unsigned short*)(ws + OFF_HB);

    {   // transposes (w1: 4096 blocks, w2: 4096) + router (2048), round-robin.
        prep_kernel<<<dim3(10240), 256, 0, stream>>>(x, gate_w, w1, w2,
                                                     w1b, w2b, xb, eidx, ew, hist8);
    }
    scatter_kernel<<<T_TOK / 256, 256, 0, stream>>>(eidx, hist8, counts, perm);
    {
        gemm1_kernel<<<dim3(32 * MAXTILES), 256, 0, stream>>>(xb, w1b, b1, counts, perm, hb);
    }
    {
        gemm2_kernel<<<dim3(8 * MAXTILES), 512, 0, stream>>>(hb, w2b, b2, counts, perm, ew, out);
    }
}